// Round 3
// baseline (1936.028 us; speedup 1.0000x reference)
//
#include <hip/hip_runtime.h>
#include <cstdint>

#define HEADS 32
#define SEQ 1024
#define HD 128
#define DMODEL 4096
#define HB 102      // heavy budget = int(0.1*1024)
#define RB 102      // recent budget
#define KEEP 101    // HB-1 (top_k k)

typedef _Float16 half8_t __attribute__((ext_vector_type(8)));
typedef _Float16 half4_t __attribute__((ext_vector_type(4)));
typedef float f32x4 __attribute__((ext_vector_type(4)));

// ---------------------------------------------------------------------------
// GEMM: C = A * B^T  (A: [M x K] row-major, B: [N x K] row-major — torch
// Linear convention y = x W^T). SPLIT=true: fp16 hi/lo 3-MFMA fp32-precision
// emulation. OUTMODE 0: C[row*N+col]. OUTMODE 1: head-scatter to [h][s][hd].
// Tiles: 128x128 per workgroup (256 thr, 4 waves 2x2, each wave 64x64, 4x4
// tiles of 16x16x32 f16 MFMA), BK=32.
// ---------------------------------------------------------------------------
template<bool SPLIT, int OUTMODE>
__global__ __launch_bounds__(256)
void gemm_f16(const float* __restrict__ Ag, const float* __restrict__ Bg,
              float* __restrict__ Cg, int K, int N,
              long sA, long sB, long sC, float scale)
{
    constexpr int NSP = SPLIT ? 2 : 1;
    __shared__ __align__(16) _Float16 AH[NSP][128][40]; // 40-half row stride: 80B (16B mult, breaks pow2 banks)
    __shared__ __align__(16) _Float16 BH[NSP][128][40];

    const int b = blockIdx.z;
    const float* A = Ag + (long)b * sA;
    const float* Bm = Bg + (long)b * sB;
    float* C = Cg + (long)b * sC;

    const int m0 = blockIdx.y * 128, n0 = blockIdx.x * 128;
    const int tid = threadIdx.x;
    const int lane = tid & 63, wid = tid >> 6;
    const int wm = (wid & 1) * 64, wn = (wid >> 1) * 64;
    const int l16 = lane & 15, quad = lane >> 4;

    f32x4 zero4 = {0.f, 0.f, 0.f, 0.f};
    f32x4 acc[4][4];
    for (int i = 0; i < 4; ++i)
        for (int j = 0; j < 4; ++j) acc[i][j] = zero4;

    const int sr = tid >> 1;          // staging row 0..127
    const int sc = (tid & 1) * 16;    // staging col offset

    for (int k0 = 0; k0 < K; k0 += 32) {
        // ---- stage A,B tiles (fp32 -> f16 hi[/lo]) ----
        const float* srcA = A + (long)(m0 + sr) * K + k0 + sc;
        const float* srcB = Bm + (long)(n0 + sr) * K + k0 + sc;
#pragma unroll
        for (int i = 0; i < 4; ++i) {
            float4 v = ((const float4*)srcA)[i];
            _Float16 h0 = (_Float16)v.x, h1 = (_Float16)v.y,
                     h2 = (_Float16)v.z, h3 = (_Float16)v.w;
            *(half4_t*)&AH[0][sr][sc + 4*i] = (half4_t){h0, h1, h2, h3};
            if (SPLIT)
                *(half4_t*)&AH[NSP-1][sr][sc + 4*i] = (half4_t){
                    (_Float16)(v.x - (float)h0), (_Float16)(v.y - (float)h1),
                    (_Float16)(v.z - (float)h2), (_Float16)(v.w - (float)h3)};
            float4 w = ((const float4*)srcB)[i];
            _Float16 g0 = (_Float16)w.x, g1 = (_Float16)w.y,
                     g2 = (_Float16)w.z, g3 = (_Float16)w.w;
            *(half4_t*)&BH[0][sr][sc + 4*i] = (half4_t){g0, g1, g2, g3};
            if (SPLIT)
                *(half4_t*)&BH[NSP-1][sr][sc + 4*i] = (half4_t){
                    (_Float16)(w.x - (float)g0), (_Float16)(w.y - (float)g1),
                    (_Float16)(w.z - (float)g2), (_Float16)(w.w - (float)g3)};
        }
        __syncthreads();

        half8_t ah[4], bh[4], al[4], bl[4];
#pragma unroll
        for (int i = 0; i < 4; ++i) {
            ah[i] = *(const half8_t*)&AH[0][wm + i*16 + l16][quad * 8];
            bh[i] = *(const half8_t*)&BH[0][wn + i*16 + l16][quad * 8];
            if (SPLIT) {
                al[i] = *(const half8_t*)&AH[NSP-1][wm + i*16 + l16][quad * 8];
                bl[i] = *(const half8_t*)&BH[NSP-1][wn + i*16 + l16][quad * 8];
            }
        }
#pragma unroll
        for (int mt = 0; mt < 4; ++mt)
#pragma unroll
            for (int nt = 0; nt < 4; ++nt) {
                acc[mt][nt] = __builtin_amdgcn_mfma_f32_16x16x32_f16(ah[mt], bh[nt], acc[mt][nt], 0, 0, 0);
                if (SPLIT) {
                    acc[mt][nt] = __builtin_amdgcn_mfma_f32_16x16x32_f16(ah[mt], bl[nt], acc[mt][nt], 0, 0, 0);
                    acc[mt][nt] = __builtin_amdgcn_mfma_f32_16x16x32_f16(al[mt], bh[nt], acc[mt][nt], 0, 0, 0);
                }
            }
        __syncthreads();
    }

    // ---- epilogue: C/D layout col=lane&15, row=quad*4+reg ----
#pragma unroll
    for (int mt = 0; mt < 4; ++mt)
#pragma unroll
        for (int nt = 0; nt < 4; ++nt)
#pragma unroll
            for (int r = 0; r < 4; ++r) {
                int row = m0 + wm + mt*16 + quad*4 + r;
                int col = n0 + wn + nt*16 + l16;
                float v = acc[mt][nt][r] * scale;
                if (OUTMODE == 0)
                    C[(long)row * N + col] = v;
                else // head scatter: col -> (head, hd); out [h][s][hd]
                    C[(long)(col >> 7) * (SEQ * HD) + (long)row * HD + (col & 127)] = v;
            }
}

// ---------------------------------------------------------------------------
// RoPE, in place on Q and K stored [h][s][hd].
// ---------------------------------------------------------------------------
__global__ __launch_bounds__(256)
void rope_kernel(float* __restrict__ Q, float* __restrict__ Kr)
{
    int idx = blockIdx.x * 256 + threadIdx.x;   // HEADS*SEQ*64
    if (idx >= HEADS * SEQ * 64) return;
    int d = idx & 63;
    int s = (idx >> 6) & (SEQ - 1);
    int h = idx >> 16;
    long base = ((long)h * SEQ + s) * HD;
    float inv = 1.0f / powf(10000.0f, (float)(2 * d) / 128.0f);  // matches jnp fp32 formula
    float ang = (float)s * inv;
    float c = cosf(ang), sn = sinf(ang);
    float q1 = Q[base + d], q2 = Q[base + d + 64];
    Q[base + d]      = q1 * c - q2 * sn;
    Q[base + d + 64] = q2 * c + q1 * sn;
    float k1 = Kr[base + d], k2 = Kr[base + d + 64];
    Kr[base + d]      = k1 * c - k2 * sn;
    Kr[base + d + 64] = k2 * c + k1 * sn;
}

// ---------------------------------------------------------------------------
// Row softmax stats. phase 1: causal only (for the H2O scan probabilities).
// phase 2: final mask = causal & (recent | heavy-bitmap) (rows<HB: causal).
// One wave per row.
// ---------------------------------------------------------------------------
__global__ __launch_bounds__(64)
void stats_kernel(const float* __restrict__ S, const uint32_t* __restrict__ mb,
                  float* __restrict__ mx_o, float* __restrict__ rd_o, int phase)
{
    int row = blockIdx.x;            // h*SEQ + t
    int t = row & (SEQ - 1);
    const float* Sr = S + (long)row * SEQ;
    const uint32_t* mrow = mb + (long)row * 32;
    int tid = threadIdx.x;
    bool use_mask = (phase == 2) && (t >= HB);

    float lm = -3.4e38f;
    for (int j = tid; j <= t; j += 64) {
        bool ok = !use_mask || (j >= t - RB) || ((mrow[j >> 5] >> (j & 31)) & 1);
        if (ok) lm = fmaxf(lm, Sr[j]);
    }
#pragma unroll
    for (int off = 32; off; off >>= 1) lm = fmaxf(lm, __shfl_xor(lm, off));

    float ls = 0.f;
    for (int j = tid; j <= t; j += 64) {
        bool ok = !use_mask || (j >= t - RB) || ((mrow[j >> 5] >> (j & 31)) & 1);
        if (ok) ls += expf(Sr[j] - lm);
    }
#pragma unroll
    for (int off = 32; off; off >>= 1) ls += __shfl_xor(ls, off);

    if (tid == 0) { mx_o[row] = lm; rd_o[row] = 1.0f / ls; }
}

// ---------------------------------------------------------------------------
// Wave64 unsigned-min reduction via DPP (VALU latency, not LDS latency).
// Canonical GCN sequence; result valid in lane 63, broadcast via readlane.
// ---------------------------------------------------------------------------
__device__ __forceinline__ uint32_t wave_umin_bcast(uint32_t v)
{
    uint32_t t;
    t = (uint32_t)__builtin_amdgcn_update_dpp((int)v, (int)v, 0x111, 0xf, 0xf, false); v = t < v ? t : v; // row_shr:1
    t = (uint32_t)__builtin_amdgcn_update_dpp((int)v, (int)v, 0x112, 0xf, 0xf, false); v = t < v ? t : v; // row_shr:2
    t = (uint32_t)__builtin_amdgcn_update_dpp((int)v, (int)v, 0x114, 0xf, 0xe, false); v = t < v ? t : v; // row_shr:4
    t = (uint32_t)__builtin_amdgcn_update_dpp((int)v, (int)v, 0x118, 0xf, 0xc, false); v = t < v ? t : v; // row_shr:8
    t = (uint32_t)__builtin_amdgcn_update_dpp((int)v, (int)v, 0x142, 0xa, 0xf, false); v = t < v ? t : v; // row_bcast:15
    t = (uint32_t)__builtin_amdgcn_update_dpp((int)v, (int)v, 0x143, 0xc, 0xf, false); v = t < v ? t : v; // row_bcast:31
    return (uint32_t)__builtin_amdgcn_readlane((int)v, 63);
}

// ---------------------------------------------------------------------------
// H2O sequential scan. One wave per head; 128 slots (2 per lane) hold acc in
// registers. Depth-3 software pipeline: per-lane loads for row t+3 issue at
// the TOP of step t keyed to current cols; cols only change via claims, and
// claims at steps t..t+3 take cols t..t+3, whose row-(t+3) values are the 4
// contiguous broadcasts S[t+3][t..t+3]. At use: col>=t-3 -> broadcast.
// Bitmap lives in registers (lane w<32 owns word w); incremental update
// (clear victim bit unless protected, set bit t on claim), one coalesced
// 128B store per step. No LDS at all, no __syncthreads (single wave).
// ---------------------------------------------------------------------------
__global__ __launch_bounds__(64)
void scan_kernel(const float* __restrict__ S, const float* __restrict__ mx1,
                 const float* __restrict__ rd1, uint32_t* __restrict__ mb)
{
    const int h = blockIdx.x, tid = threadIdx.x;
    const float* Sh = S + (long)h * SEQ * SEQ;
    const float* mx = mx1 + h * SEQ;
    const float* rd = rd1 + h * SEQ;

    int col0 = tid, col1 = 64 + tid;
    bool al0 = true, al1 = (col1 < HB);
    float ac0 = 0.f, ac1 = 0.f;

    // acc[j] = sum_{t=j..HB-1} softmax_row_t[j]  (coalesced: col = lane)
    for (int t = 0; t < HB; ++t) {
        float m = mx[t], r = rd[t];
        if (t >= col0) ac0 += __expf(Sh[(long)t * SEQ + col0] - m) * r;
        if (al1 && t >= col1) ac1 += __expf(Sh[(long)t * SEQ + col1] - m) * r;
    }

    // bitmap in registers: lane w (w<32) owns cols [32w, 32w+32); init cols 0..101
    uint32_t bmw = (tid < 3) ? 0xFFFFFFFFu : (tid == 3 ? 0x3Fu : 0u);

    // ---- prime the depth-3 pipeline (use-rows HB, HB+1, HB+2) ----
    float x0a, x0b, x0c, x1a, x1b, x1c;
    f32x4 bqa, bqb, bqc;
    float mqa, mqb, mqc, rqa, rqb, rqc;
    {
        const float* r0 = Sh + (long)(HB + 0) * SEQ;
        const float* r1 = Sh + (long)(HB + 1) * SEQ;
        const float* r2 = Sh + (long)(HB + 2) * SEQ;
        x0a = r0[col0]; x1a = r0[col1];
        x0b = r1[col0]; x1b = r1[col1];
        x0c = r2[col0]; x1c = r2[col1];
        bqa = (f32x4){r0[HB - 3], r0[HB - 2], r0[HB - 1], r0[HB + 0]};
        bqb = (f32x4){r1[HB - 2], r1[HB - 1], r1[HB + 0], r1[HB + 1]};
        bqc = (f32x4){r2[HB - 1], r2[HB + 0], r2[HB + 1], r2[HB + 2]};
        mqa = mx[HB]; mqb = mx[HB + 1]; mqc = mx[HB + 2];
        rqa = rd[HB]; rqb = rd[HB + 1]; rqc = rd[HB + 2];
    }

    int P = HB;
    for (int t = HB; t < SEQ; ++t) {
        // ---- issue prefetch for row t+3 (pre-extract cols; claims covered
        //      by the 4 broadcasts) ----
        int u = t + 3; if (u > SEQ - 1) u = SEQ - 1;
        const float* Sn = Sh + (long)u * SEQ;
        float nx0 = Sn[col0], nx1 = Sn[col1];
        f32x4 nbq = (f32x4){Sn[u - 3], Sn[u - 2], Sn[u - 1], Sn[u]};
        float nmq = mx[u], nrq = rd[u];

        // ---- extract (P-101) victims; steady state: exactly 1 ----
        uint32_t k0 = al0 ? __float_as_uint(ac0) : 0xFFFFFFFFu;
        uint32_t k1 = al1 ? __float_as_uint(ac1) : 0xFFFFFFFFu;
        int nex = P - KEEP;
        for (int e = 0; e < nex; ++e) {
            uint32_t mn = wave_umin_bcast(k0 < k1 ? k0 : k1);
            bool hit0 = (k0 == mn), hit1 = (k1 == mn);
            unsigned long long b0 = __ballot(hit0), b1 = __ballot(hit1);
            int vc;
            if (__popcll(b0) + __popcll(b1) > 1) {
                // exact-tie path (rare): drop the LARGEST col among candidates
                int c = hit0 ? col0 : -1;
                int c2 = hit1 ? col1 : -1;
                c = c > c2 ? c : c2;
#pragma unroll
                for (int off = 32; off; off >>= 1) {
                    int o = __shfl_xor(c, off);
                    c = o > c ? o : c;
                }
                hit0 = hit0 && (col0 == c);
                hit1 = hit1 && (col1 == c) && !hit0;
                vc = c;
            } else {
                int ln = (int)(__ffsll(b0 | b1) - 1);
                int vsel = hit0 ? col0 : col1;
                vc = __shfl(vsel, ln);
            }
            if (hit0)      { k0 = 0xFFFFFFFFu; if (col0 >= 4) al0 = false; }
            else if (hit1) { k1 = 0xFFFFFFFFu; if (col1 >= 4) al1 = false; }
            // clear victim's bitmap bit unless protected (cols<4 stay)
            if (vc >= 4 && tid == (vc >> 5)) bmw &= ~(1u << (vc & 31));
        }

        // ---- claim one dead slot for col t ----
        bool claimed0 = false, claimed1 = false;
        unsigned long long d0 = __ballot(!al0);
        unsigned long long d1 = __ballot(!al1);
        if (d0)      claimed0 = (tid == __ffsll(d0) - 1);
        else if (d1) claimed1 = (tid == __ffsll(d1) - 1);
        if (claimed0) { col0 = t; ac0 = 0.f; al0 = true; }
        if (claimed1) { col1 = t; ac1 = 0.f; al1 = true; }
        if ((d0 | d1) && tid == (t >> 5)) bmw |= 1u << (t & 31);
        P = __popcll(__ballot(al0)) + __popcll(__ballot(al1));

        // ---- accumulate probs of row t (values from pipeline head) ----
        float v0 = x0a;
        int j0 = col0 - (t - 3);
        if (j0 >= 0) v0 = (j0 == 3) ? bqa[3] : (j0 == 2) ? bqa[2] : (j0 == 1) ? bqa[1] : bqa[0];
        float v1 = x1a;
        int j1 = col1 - (t - 3);
        if (j1 >= 0) v1 = (j1 == 3) ? bqa[3] : (j1 == 2) ? bqa[2] : (j1 == 1) ? bqa[1] : bqa[0];
        if (al0) ac0 += __expf(v0 - mqa) * rqa;
        if (al1) ac1 += __expf(v1 - mqa) * rqa;

        // ---- store bitmap for row t (coalesced 128B, fire & forget) ----
        if (tid < 32) mb[((long)h * SEQ + t) * 32 + tid] = bmw;

        // ---- rotate pipeline ----
        x0a = x0b; x0b = x0c; x0c = nx0;
        x1a = x1b; x1b = x1c; x1c = nx1;
        bqa = bqb; bqb = bqc; bqc = nbq;
        mqa = mqb; mqb = mqc; mqc = nmq;
        rqa = rqb; rqb = rqc; rqc = nrq;
    }
}

// ---------------------------------------------------------------------------
// PV: ctx[s][h][hd] = sum_j P[h][s][j] * V[h][j][hd], P built on the fly from
// S + mask + stats2, f16 MFMA. WG = 64 q-rows x 128 hd, j-tiles of 64.
// ---------------------------------------------------------------------------
__global__ __launch_bounds__(256)
void pv_kernel(const float* __restrict__ S, const float* __restrict__ V,
               const uint32_t* __restrict__ mb, const float* __restrict__ mx2,
               const float* __restrict__ rd2, float* __restrict__ ctx)
{
    const int rb = blockIdx.x, h = blockIdx.y;
    const int tid = threadIdx.x, lane = tid & 63, wid = tid >> 6;
    const int wm = (wid & 1) * 32, wn = (wid >> 1) * 64;
    const int l16 = lane & 15, quad = lane >> 4;
    __shared__ __align__(16) _Float16 PT[64][72];
    __shared__ __align__(16) _Float16 VT[128][72];

    const int m0 = rb * 64;
    f32x4 zero4 = {0.f, 0.f, 0.f, 0.f};
    f32x4 acc[2][4];
    for (int i = 0; i < 2; ++i)
        for (int j = 0; j < 4; ++j) acc[i][j] = zero4;

    const float* Sh = S + ((long)h * SEQ + m0) * SEQ;
    const float* Vh = V + (long)h * SEQ * HD;

    const int pr = tid >> 2, pc = (tid & 3) * 16;  // P staging: row, col base
    const int trow = m0 + pr;
    const float pmx = mx2[h * SEQ + trow], prd = rd2[h * SEQ + trow];
    const uint32_t* mrow = mb + ((long)h * SEQ + trow) * 32;
    const bool use_mask = (trow >= HB);

    for (int jt = 0; jt <= rb; ++jt) {
        int j0 = jt * 64;
        // stage P tile (probabilities) as f16, A-operand layout [m][k]
#pragma unroll
        for (int i = 0; i < 4; ++i) {
            float4 v = *(const float4*)(Sh + (long)pr * SEQ + j0 + pc + i * 4);
#pragma unroll
            for (int u = 0; u < 4; ++u) {
                int j = j0 + pc + i * 4 + u;
                float s = (u == 0) ? v.x : (u == 1) ? v.y : (u == 2) ? v.z : v.w;
                bool ok = (j <= trow) &&
                          (!use_mask || j >= trow - RB || ((mrow[j >> 5] >> (j & 31)) & 1));
                float p = ok ? expf(s - pmx) * prd : 0.f;
                PT[pr][pc + i * 4 + u] = (_Float16)p;
            }
        }
        // stage V tile transposed: VT[hd][j], B-operand layout
#pragma unroll
        for (int i = 0; i < 8; ++i) {
            int flat = i * 256 + tid;
            int j = flat >> 5, c4 = (flat & 31) * 4;
            float4 v = *(const float4*)(Vh + (long)(j0 + j) * HD + c4);
            VT[c4 + 0][j] = (_Float16)v.x;
            VT[c4 + 1][j] = (_Float16)v.y;
            VT[c4 + 2][j] = (_Float16)v.z;
            VT[c4 + 3][j] = (_Float16)v.w;
        }
        __syncthreads();
#pragma unroll
        for (int ks = 0; ks < 2; ++ks) {
            half8_t a[2], bf[4];
#pragma unroll
            for (int i = 0; i < 2; ++i)
                a[i] = *(const half8_t*)&PT[wm + i * 16 + l16][ks * 32 + quad * 8];
#pragma unroll
            for (int i = 0; i < 4; ++i)
                bf[i] = *(const half8_t*)&VT[wn + i * 16 + l16][ks * 32 + quad * 8];
#pragma unroll
            for (int mt = 0; mt < 2; ++mt)
#pragma unroll
                for (int nt = 0; nt < 4; ++nt)
                    acc[mt][nt] = __builtin_amdgcn_mfma_f32_16x16x32_f16(a[mt], bf[nt], acc[mt][nt], 0, 0, 0);
        }
        __syncthreads();
    }
    // write ctx [s][h*HD+hd]
#pragma unroll
    for (int mt = 0; mt < 2; ++mt)
#pragma unroll
        for (int nt = 0; nt < 4; ++nt)
#pragma unroll
            for (int r = 0; r < 4; ++r) {
                int s_ = m0 + wm + mt * 16 + quad * 4 + r;
                int hd = wn + nt * 16 + l16;
                ctx[(long)s_ * DMODEL + h * HD + hd] = acc[mt][nt][r];
            }
}

// ---------------------------------------------------------------------------
extern "C" void kernel_launch(void* const* d_in, const int* in_sizes, int n_in,
                              void* d_out, int out_size, void* d_ws, size_t ws_size,
                              hipStream_t stream)
{
    const float* hs = (const float*)d_in[0];
    // d_in[1] = attention_mask: structure known (causal), not needed
    const float* Wq = (const float*)d_in[2];
    const float* Wk = (const float*)d_in[3];
    const float* Wv = (const float*)d_in[4];
    const float* Wo = (const float*)d_in[5];
    float* out = (float*)d_out;

    char* w = (char*)d_ws;
    float* Qr  = (float*)w;  w += (long)HEADS * SEQ * HD * 4;   // 16MB
    float* Kr  = (float*)w;  w += (long)HEADS * SEQ * HD * 4;   // 16MB
    float* V   = (float*)w;  w += (long)HEADS * SEQ * HD * 4;   // 16MB
    float* ctx = (float*)w;  w += (long)SEQ * DMODEL * 4;       // 16MB
    float* mx1 = (float*)w;  w += (long)HEADS * SEQ * 4;
    float* rd1 = (float*)w;  w += (long)HEADS * SEQ * 4;
    float* mx2 = (float*)w;  w += (long)HEADS * SEQ * 4;
    float* rd2 = (float*)w;  w += (long)HEADS * SEQ * 4;
    uint32_t* mb = (uint32_t*)w; w += (long)HEADS * SEQ * 32 * 4; // 4MB
    float* S   = (float*)w;  w += (long)HEADS * SEQ * SEQ * 4;  // 134MB

    const float inv_sqrt_hd = 0.088388347648318447f; // 1/sqrt(128)

    dim3 gproj(DMODEL / 128, SEQ / 128, 1);
    // Q,K: fp32-precision split GEMM (mask decisions depend on them)
    gemm_f16<true, 1><<<gproj, 256, 0, stream>>>(hs, Wq, Qr, DMODEL, DMODEL, 0, 0, 0, 1.f);
    gemm_f16<true, 1><<<gproj, 256, 0, stream>>>(hs, Wk, Kr, DMODEL, DMODEL, 0, 0, 0, 1.f);
    // V: plain f16 MFMA
    gemm_f16<false, 1><<<gproj, 256, 0, stream>>>(hs, Wv, V, DMODEL, DMODEL, 0, 0, 0, 1.f);

    rope_kernel<<<(HEADS * SEQ * 64) / 256, 256, 0, stream>>>(Qr, Kr);

    // S = Q K^T / sqrt(hd), split precision, batched over heads
    dim3 gsc(SEQ / 128, SEQ / 128, HEADS);
    gemm_f16<true, 0><<<gsc, 256, 0, stream>>>(Qr, Kr, S, HD, SEQ,
        (long)SEQ * HD, (long)SEQ * HD, (long)SEQ * SEQ, inv_sqrt_hd);

    stats_kernel<<<HEADS * SEQ, 64, 0, stream>>>(S, mb, mx1, rd1, 1);
    scan_kernel<<<HEADS, 64, 0, stream>>>(S, mx1, rd1, mb);
    stats_kernel<<<HEADS * SEQ, 64, 0, stream>>>(S, mb, mx2, rd2, 2);
    pv_kernel<<<dim3(SEQ / 64, HEADS), 256, 0, stream>>>(S, V, mb, mx2, rd2, ctx);

    // out = ctx Wo^T
    gemm_f16<false, 0><<<gproj, 256, 0, stream>>>(ctx, Wo, out, DMODEL, DMODEL, 0, 0, 0, 1.f);
}

// Round 4
// 1749.438 us; speedup vs baseline: 1.1067x; 1.1067x over previous
//
#include <hip/hip_runtime.h>
#include <cstdint>

#define HEADS 32
#define SEQ 1024
#define HD 128
#define DMODEL 4096
#define HB 102      // heavy budget = int(0.1*1024)
#define RB 102      // recent budget
#define KEEP 101    // HB-1 (top_k k)

typedef _Float16 half8_t __attribute__((ext_vector_type(8)));
typedef _Float16 half4_t __attribute__((ext_vector_type(4)));
typedef float f32x4 __attribute__((ext_vector_type(4)));

// ---------------------------------------------------------------------------
// GEMM: C = A * B^T  (A: [M x K] row-major, B: [N x K] row-major — torch
// Linear convention y = x W^T). SPLIT=true: fp16 hi/lo 3-MFMA fp32-precision
// emulation. OUTMODE 0: C[row*N+col]. OUTMODE 1: head-scatter to [h][s][hd].
// Tiles: 128x128 per workgroup (256 thr, 4 waves 2x2, each wave 64x64, 4x4
// tiles of 16x16x32 f16 MFMA), BK=32.
// ---------------------------------------------------------------------------
template<bool SPLIT, int OUTMODE>
__global__ __launch_bounds__(256)
void gemm_f16(const float* __restrict__ Ag, const float* __restrict__ Bg,
              float* __restrict__ Cg, int K, int N,
              long sA, long sB, long sC, float scale)
{
    constexpr int NSP = SPLIT ? 2 : 1;
    __shared__ __align__(16) _Float16 AH[NSP][128][40]; // 40-half row stride: 80B (16B mult, breaks pow2 banks)
    __shared__ __align__(16) _Float16 BH[NSP][128][40];

    const int b = blockIdx.z;
    const float* A = Ag + (long)b * sA;
    const float* Bm = Bg + (long)b * sB;
    float* C = Cg + (long)b * sC;

    const int m0 = blockIdx.y * 128, n0 = blockIdx.x * 128;
    const int tid = threadIdx.x;
    const int lane = tid & 63, wid = tid >> 6;
    const int wm = (wid & 1) * 64, wn = (wid >> 1) * 64;
    const int l16 = lane & 15, quad = lane >> 4;

    f32x4 zero4 = {0.f, 0.f, 0.f, 0.f};
    f32x4 acc[4][4];
    for (int i = 0; i < 4; ++i)
        for (int j = 0; j < 4; ++j) acc[i][j] = zero4;

    const int sr = tid >> 1;          // staging row 0..127
    const int sc = (tid & 1) * 16;    // staging col offset

    for (int k0 = 0; k0 < K; k0 += 32) {
        // ---- stage A,B tiles (fp32 -> f16 hi[/lo]) ----
        const float* srcA = A + (long)(m0 + sr) * K + k0 + sc;
        const float* srcB = Bm + (long)(n0 + sr) * K + k0 + sc;
#pragma unroll
        for (int i = 0; i < 4; ++i) {
            float4 v = ((const float4*)srcA)[i];
            _Float16 h0 = (_Float16)v.x, h1 = (_Float16)v.y,
                     h2 = (_Float16)v.z, h3 = (_Float16)v.w;
            *(half4_t*)&AH[0][sr][sc + 4*i] = (half4_t){h0, h1, h2, h3};
            if (SPLIT)
                *(half4_t*)&AH[NSP-1][sr][sc + 4*i] = (half4_t){
                    (_Float16)(v.x - (float)h0), (_Float16)(v.y - (float)h1),
                    (_Float16)(v.z - (float)h2), (_Float16)(v.w - (float)h3)};
            float4 w = ((const float4*)srcB)[i];
            _Float16 g0 = (_Float16)w.x, g1 = (_Float16)w.y,
                     g2 = (_Float16)w.z, g3 = (_Float16)w.w;
            *(half4_t*)&BH[0][sr][sc + 4*i] = (half4_t){g0, g1, g2, g3};
            if (SPLIT)
                *(half4_t*)&BH[NSP-1][sr][sc + 4*i] = (half4_t){
                    (_Float16)(w.x - (float)g0), (_Float16)(w.y - (float)g1),
                    (_Float16)(w.z - (float)g2), (_Float16)(w.w - (float)g3)};
        }
        __syncthreads();

        half8_t ah[4], bh[4], al[4], bl[4];
#pragma unroll
        for (int i = 0; i < 4; ++i) {
            ah[i] = *(const half8_t*)&AH[0][wm + i*16 + l16][quad * 8];
            bh[i] = *(const half8_t*)&BH[0][wn + i*16 + l16][quad * 8];
            if (SPLIT) {
                al[i] = *(const half8_t*)&AH[NSP-1][wm + i*16 + l16][quad * 8];
                bl[i] = *(const half8_t*)&BH[NSP-1][wn + i*16 + l16][quad * 8];
            }
        }
#pragma unroll
        for (int mt = 0; mt < 4; ++mt)
#pragma unroll
            for (int nt = 0; nt < 4; ++nt) {
                acc[mt][nt] = __builtin_amdgcn_mfma_f32_16x16x32_f16(ah[mt], bh[nt], acc[mt][nt], 0, 0, 0);
                if (SPLIT) {
                    acc[mt][nt] = __builtin_amdgcn_mfma_f32_16x16x32_f16(ah[mt], bl[nt], acc[mt][nt], 0, 0, 0);
                    acc[mt][nt] = __builtin_amdgcn_mfma_f32_16x16x32_f16(al[mt], bh[nt], acc[mt][nt], 0, 0, 0);
                }
            }
        __syncthreads();
    }

    // ---- epilogue: C/D layout col=lane&15, row=quad*4+reg ----
#pragma unroll
    for (int mt = 0; mt < 4; ++mt)
#pragma unroll
        for (int nt = 0; nt < 4; ++nt)
#pragma unroll
            for (int r = 0; r < 4; ++r) {
                int row = m0 + wm + mt*16 + quad*4 + r;
                int col = n0 + wn + nt*16 + l16;
                float v = acc[mt][nt][r] * scale;
                if (OUTMODE == 0)
                    C[(long)row * N + col] = v;
                else // head scatter: col -> (head, hd); out [h][s][hd]
                    C[(long)(col >> 7) * (SEQ * HD) + (long)row * HD + (col & 127)] = v;
            }
}

// ---------------------------------------------------------------------------
// RoPE, in place on Q and K stored [h][s][hd].
// ---------------------------------------------------------------------------
__global__ __launch_bounds__(256)
void rope_kernel(float* __restrict__ Q, float* __restrict__ Kr)
{
    int idx = blockIdx.x * 256 + threadIdx.x;   // HEADS*SEQ*64
    if (idx >= HEADS * SEQ * 64) return;
    int d = idx & 63;
    int s = (idx >> 6) & (SEQ - 1);
    int h = idx >> 16;
    long base = ((long)h * SEQ + s) * HD;
    float inv = 1.0f / powf(10000.0f, (float)(2 * d) / 128.0f);  // matches jnp fp32 formula
    float ang = (float)s * inv;
    float c = cosf(ang), sn = sinf(ang);
    float q1 = Q[base + d], q2 = Q[base + d + 64];
    Q[base + d]      = q1 * c - q2 * sn;
    Q[base + d + 64] = q2 * c + q1 * sn;
    float k1 = Kr[base + d], k2 = Kr[base + d + 64];
    Kr[base + d]      = k1 * c - k2 * sn;
    Kr[base + d + 64] = k2 * c + k1 * sn;
}

// ---------------------------------------------------------------------------
// Row softmax stats. phase 1: causal only (for the H2O scan probabilities).
// phase 2: final mask = causal & (recent | heavy-bitmap) (rows<HB: causal).
// One wave per row.
// ---------------------------------------------------------------------------
__global__ __launch_bounds__(64)
void stats_kernel(const float* __restrict__ S, const uint32_t* __restrict__ mb,
                  float* __restrict__ mx_o, float* __restrict__ rd_o, int phase)
{
    int row = blockIdx.x;            // h*SEQ + t
    int t = row & (SEQ - 1);
    const float* Sr = S + (long)row * SEQ;
    const uint32_t* mrow = mb + (long)row * 32;
    int tid = threadIdx.x;
    bool use_mask = (phase == 2) && (t >= HB);

    float lm = -3.4e38f;
    for (int j = tid; j <= t; j += 64) {
        bool ok = !use_mask || (j >= t - RB) || ((mrow[j >> 5] >> (j & 31)) & 1);
        if (ok) lm = fmaxf(lm, Sr[j]);
    }
#pragma unroll
    for (int off = 32; off; off >>= 1) lm = fmaxf(lm, __shfl_xor(lm, off));

    float ls = 0.f;
    for (int j = tid; j <= t; j += 64) {
        bool ok = !use_mask || (j >= t - RB) || ((mrow[j >> 5] >> (j & 31)) & 1);
        if (ok) ls += expf(Sr[j] - lm);
    }
#pragma unroll
    for (int off = 32; off; off >>= 1) ls += __shfl_xor(ls, off);

    if (tid == 0) { mx_o[row] = lm; rd_o[row] = 1.0f / ls; }
}

// ---------------------------------------------------------------------------
// Wave64 unsigned-min reduction via DPP (VALU latency, not LDS latency).
// Canonical GCN sequence; result valid in lane 63, broadcast via readlane.
// ---------------------------------------------------------------------------
__device__ __forceinline__ uint32_t wave_umin_bcast(uint32_t v)
{
    uint32_t t;
    t = (uint32_t)__builtin_amdgcn_update_dpp((int)v, (int)v, 0x111, 0xf, 0xf, false); v = t < v ? t : v; // row_shr:1
    t = (uint32_t)__builtin_amdgcn_update_dpp((int)v, (int)v, 0x112, 0xf, 0xf, false); v = t < v ? t : v; // row_shr:2
    t = (uint32_t)__builtin_amdgcn_update_dpp((int)v, (int)v, 0x114, 0xf, 0xe, false); v = t < v ? t : v; // row_shr:4
    t = (uint32_t)__builtin_amdgcn_update_dpp((int)v, (int)v, 0x118, 0xf, 0xc, false); v = t < v ? t : v; // row_shr:8
    t = (uint32_t)__builtin_amdgcn_update_dpp((int)v, (int)v, 0x142, 0xa, 0xf, false); v = t < v ? t : v; // row_bcast:15
    t = (uint32_t)__builtin_amdgcn_update_dpp((int)v, (int)v, 0x143, 0xc, 0xf, false); v = t < v ? t : v; // row_bcast:31
    return (uint32_t)__builtin_amdgcn_readlane((int)v, 63);
}

// ---------------------------------------------------------------------------
// H2O sequential scan. One wave per head; 128 slots (2 per lane) hold acc in
// registers.
//
// Round-3 lesson: uniform-address loads (mx[u], rd[u], Sn[u-3..u]) get
// compiled to out-of-order SMEM s_loads -> conservative lgkmcnt(0) per step,
// and end-of-body register rotation forces vmcnt(0) per step. Both defeated
// the pipeline. This version:
//   - mx/rd staged once into LDS; per-step ds_read (in-order DS pipe).
//   - diagonal correction quad S[u][u-3..u] loaded as a PER-LANE vector load
//     (lane&3 duplication), element pulled at use via ds_bpermute.
//   - 6-slot modulo register pipeline (read slot s, write slot s+3),
//     unrolled x6: disjoint registers, no rotation moves, loads land
//     directly in their final registers -> fine-grained vmcnt.
//   - victim-col broadcast via readlane (SGPR index) instead of ds_bpermute.
// Bitmap in registers (lane w<32 owns word w), one coalesced store per step.
// ---------------------------------------------------------------------------
__global__ __launch_bounds__(64)
void scan_kernel(const float* __restrict__ S, const float* __restrict__ mx1,
                 const float* __restrict__ rd1, uint32_t* __restrict__ mb)
{
    const int h = blockIdx.x, tid = threadIdx.x;
    const float* Sh = S + (long)h * SEQ * SEQ;
    const float* mx = mx1 + h * SEQ;
    const float* rd = rd1 + h * SEQ;

    __shared__ float smx[SEQ];
    __shared__ float srd[SEQ];
    for (int i = tid; i < SEQ; i += 64) { smx[i] = mx[i]; srd[i] = rd[i]; }
    // single wave: DS pipe is in-order; compiler inserts the lgkm wait.

    int col0 = tid, col1 = 64 + tid;
    bool al0 = true, al1 = (col1 < HB);
    float ac0 = 0.f, ac1 = 0.f;

    // acc[j] = sum_{t=j..HB-1} softmax_row_t[j]  (coalesced: col = lane)
#pragma unroll 4
    for (int t = 0; t < HB; ++t) {
        float m = smx[t], r = srd[t];
        if (t >= col0) ac0 += __expf(Sh[(long)t * SEQ + col0] - m) * r;
        if (al1 && t >= col1) ac1 += __expf(Sh[(long)t * SEQ + col1] - m) * r;
    }

    // bitmap in registers: lane w (w<32) owns cols [32w, 32w+32); init cols 0..101
    uint32_t bmw = (tid < 3) ? 0xFFFFFFFFu : (tid == 3 ? 0x3Fu : 0u);

    // ---- 6-slot pipeline state (use-row for slot s at step t: (t-HB)%6==s) ----
    float x0[6], x1[6], nb[6], mq[6], rq[6];
    // prime slots 0..2 with rows HB..HB+2
#pragma unroll
    for (int s = 0; s < 3; ++s) {
        const float* r0 = Sh + (long)(HB + s) * SEQ;
        x0[s] = r0[col0];
        x1[s] = r0[col1];
        nb[s] = r0[HB + s - 3 + (tid & 3)];   // lane&3 duplication of the diag quad
        mq[s] = smx[HB + s];
        rq[s] = srd[HB + s];
    }
#pragma unroll
    for (int s = 3; s < 6; ++s) { x0[s] = 0.f; x1[s] = 0.f; nb[s] = 0.f; mq[s] = 0.f; rq[s] = 1.f; }

    int P = HB;
    for (int tb = HB; tb < SEQ; tb += 6) {
#pragma unroll
        for (int s = 0; s < 6; ++s) {
            const int t = tb + s;
            if (t < SEQ) {
                const int ws = (s + 3) % 6;    // slot being filled (row t+3)
                int u = t + 3; if (u > SEQ - 1) u = SEQ - 1;
                const float* Sn = Sh + (long)u * SEQ;

                // ---- issue vector prefetch straight into slot-ws registers ----
                x0[ws] = Sn[col0];
                x1[ws] = Sn[col1];
                nb[ws] = Sn[u - 3 + (tid & 3)];

                // ---- extract (P-101) victims; steady state: exactly 1 ----
                uint32_t k0 = al0 ? __float_as_uint(ac0) : 0xFFFFFFFFu;
                uint32_t k1 = al1 ? __float_as_uint(ac1) : 0xFFFFFFFFu;
                int nex = P - KEEP;
                for (int e = 0; e < nex; ++e) {
                    uint32_t mn = wave_umin_bcast(k0 < k1 ? k0 : k1);
                    bool hit0 = (k0 == mn), hit1 = (k1 == mn);
                    unsigned long long b0 = __ballot(hit0), b1 = __ballot(hit1);
                    int vc;
                    if (__popcll(b0) + __popcll(b1) > 1) {
                        // exact-tie path (rare): drop the LARGEST col among candidates
                        int c = hit0 ? col0 : -1;
                        int c2 = hit1 ? col1 : -1;
                        c = c > c2 ? c : c2;
#pragma unroll
                        for (int off = 32; off; off >>= 1) {
                            int o = __shfl_xor(c, off);
                            c = o > c ? o : c;
                        }
                        hit0 = hit0 && (col0 == c);
                        hit1 = hit1 && (col1 == c) && !hit0;
                        vc = c;
                    } else {
                        int ln = (int)(__ffsll(b0 | b1) - 1);
                        int vsel = hit0 ? col0 : col1;
                        vc = __builtin_amdgcn_readlane(vsel, ln);
                    }
                    if (hit0)      { k0 = 0xFFFFFFFFu; if (col0 >= 4) al0 = false; }
                    else if (hit1) { k1 = 0xFFFFFFFFu; if (col1 >= 4) al1 = false; }
                    // clear victim's bitmap bit unless protected (cols<4 stay)
                    if (vc >= 4 && tid == (vc >> 5)) bmw &= ~(1u << (vc & 31));
                }

                // ---- claim one dead slot for col t ----
                bool claimed0 = false, claimed1 = false;
                unsigned long long d0 = __ballot(!al0);
                unsigned long long d1 = __ballot(!al1);
                if (d0)      claimed0 = (tid == __ffsll(d0) - 1);
                else if (d1) claimed1 = (tid == __ffsll(d1) - 1);
                if (claimed0) { col0 = t; ac0 = 0.f; al0 = true; }
                if (claimed1) { col1 = t; ac1 = 0.f; al1 = true; }
                if ((d0 | d1) && tid == (t >> 5)) bmw |= 1u << (t & 31);
                P = __popcll(__ballot(al0)) + __popcll(__ballot(al1));

                // ---- accumulate probs of row t (slot-s values, 3 steps old) ----
                // cols changed in steps t-3..t are exactly t-3..t -> correction
                // element S[t][t-3+j] lives in lane j of nb[s] (ds_bpermute pull).
                int j0 = col0 - (t - 3);
                int j1 = col1 - (t - 3);
                float c0 = __uint_as_float((uint32_t)__builtin_amdgcn_ds_bpermute(
                               (j0 < 0 ? 0 : j0) << 2, (int)__float_as_uint(nb[s])));
                float c1 = __uint_as_float((uint32_t)__builtin_amdgcn_ds_bpermute(
                               (j1 < 0 ? 0 : j1) << 2, (int)__float_as_uint(nb[s])));
                float v0 = (j0 >= 0) ? c0 : x0[s];
                float v1 = (j1 >= 0) ? c1 : x1[s];
                if (al0) ac0 += __expf(v0 - mq[s]) * rq[s];
                if (al1) ac1 += __expf(v1 - mq[s]) * rq[s];

                // ---- refill slot-ws softmax stats from LDS (in-order DS) ----
                mq[ws] = smx[u];
                rq[ws] = srd[u];

                // ---- store bitmap for row t (coalesced 128B, fire & forget) ----
                if (tid < 32) mb[((long)h * SEQ + t) * 32 + tid] = bmw;
            }
        }
    }
}

// ---------------------------------------------------------------------------
// PV: ctx[s][h][hd] = sum_j P[h][s][j] * V[h][j][hd], P built on the fly from
// S + mask + stats2, f16 MFMA. WG = 64 q-rows x 128 hd, j-tiles of 64.
// ---------------------------------------------------------------------------
__global__ __launch_bounds__(256)
void pv_kernel(const float* __restrict__ S, const float* __restrict__ V,
               const uint32_t* __restrict__ mb, const float* __restrict__ mx2,
               const float* __restrict__ rd2, float* __restrict__ ctx)
{
    const int rb = blockIdx.x, h = blockIdx.y;
    const int tid = threadIdx.x, lane = tid & 63, wid = tid >> 6;
    const int wm = (wid & 1) * 32, wn = (wid >> 1) * 64;
    const int l16 = lane & 15, quad = lane >> 4;
    __shared__ __align__(16) _Float16 PT[64][72];
    __shared__ __align__(16) _Float16 VT[128][72];

    const int m0 = rb * 64;
    f32x4 zero4 = {0.f, 0.f, 0.f, 0.f};
    f32x4 acc[2][4];
    for (int i = 0; i < 2; ++i)
        for (int j = 0; j < 4; ++j) acc[i][j] = zero4;

    const float* Sh = S + ((long)h * SEQ + m0) * SEQ;
    const float* Vh = V + (long)h * SEQ * HD;

    const int pr = tid >> 2, pc = (tid & 3) * 16;  // P staging: row, col base
    const int trow = m0 + pr;
    const float pmx = mx2[h * SEQ + trow], prd = rd2[h * SEQ + trow];
    const uint32_t* mrow = mb + ((long)h * SEQ + trow) * 32;
    const bool use_mask = (trow >= HB);

    for (int jt = 0; jt <= rb; ++jt) {
        int j0 = jt * 64;
        // stage P tile (probabilities) as f16, A-operand layout [m][k]
#pragma unroll
        for (int i = 0; i < 4; ++i) {
            float4 v = *(const float4*)(Sh + (long)pr * SEQ + j0 + pc + i * 4);
#pragma unroll
            for (int u = 0; u < 4; ++u) {
                int j = j0 + pc + i * 4 + u;
                float s = (u == 0) ? v.x : (u == 1) ? v.y : (u == 2) ? v.z : v.w;
                bool ok = (j <= trow) &&
                          (!use_mask || j >= trow - RB || ((mrow[j >> 5] >> (j & 31)) & 1));
                float p = ok ? expf(s - pmx) * prd : 0.f;
                PT[pr][pc + i * 4 + u] = (_Float16)p;
            }
        }
        // stage V tile transposed: VT[hd][j], B-operand layout
#pragma unroll
        for (int i = 0; i < 8; ++i) {
            int flat = i * 256 + tid;
            int j = flat >> 5, c4 = (flat & 31) * 4;
            float4 v = *(const float4*)(Vh + (long)(j0 + j) * HD + c4);
            VT[c4 + 0][j] = (_Float16)v.x;
            VT[c4 + 1][j] = (_Float16)v.y;
            VT[c4 + 2][j] = (_Float16)v.z;
            VT[c4 + 3][j] = (_Float16)v.w;
        }
        __syncthreads();
#pragma unroll
        for (int ks = 0; ks < 2; ++ks) {
            half8_t a[2], bf[4];
#pragma unroll
            for (int i = 0; i < 2; ++i)
                a[i] = *(const half8_t*)&PT[wm + i * 16 + l16][ks * 32 + quad * 8];
#pragma unroll
            for (int i = 0; i < 4; ++i)
                bf[i] = *(const half8_t*)&VT[wn + i * 16 + l16][ks * 32 + quad * 8];
#pragma unroll
            for (int mt = 0; mt < 2; ++mt)
#pragma unroll
                for (int nt = 0; nt < 4; ++nt)
                    acc[mt][nt] = __builtin_amdgcn_mfma_f32_16x16x32_f16(a[mt], bf[nt], acc[mt][nt], 0, 0, 0);
        }
        __syncthreads();
    }
    // write ctx [s][h*HD+hd]
#pragma unroll
    for (int mt = 0; mt < 2; ++mt)
#pragma unroll
        for (int nt = 0; nt < 4; ++nt)
#pragma unroll
            for (int r = 0; r < 4; ++r) {
                int s_ = m0 + wm + mt * 16 + quad * 4 + r;
                int hd = wn + nt * 16 + l16;
                ctx[(long)s_ * DMODEL + h * HD + hd] = acc[mt][nt][r];
            }
}

// ---------------------------------------------------------------------------
extern "C" void kernel_launch(void* const* d_in, const int* in_sizes, int n_in,
                              void* d_out, int out_size, void* d_ws, size_t ws_size,
                              hipStream_t stream)
{
    const float* hs = (const float*)d_in[0];
    // d_in[1] = attention_mask: structure known (causal), not needed
    const float* Wq = (const float*)d_in[2];
    const float* Wk = (const float*)d_in[3];
    const float* Wv = (const float*)d_in[4];
    const float* Wo = (const float*)d_in[5];
    float* out = (float*)d_out;

    char* w = (char*)d_ws;
    float* Qr  = (float*)w;  w += (long)HEADS * SEQ * HD * 4;   // 16MB
    float* Kr  = (float*)w;  w += (long)HEADS * SEQ * HD * 4;   // 16MB
    float* V   = (float*)w;  w += (long)HEADS * SEQ * HD * 4;   // 16MB
    float* ctx = (float*)w;  w += (long)SEQ * DMODEL * 4;       // 16MB
    float* mx1 = (float*)w;  w += (long)HEADS * SEQ * 4;
    float* rd1 = (float*)w;  w += (long)HEADS * SEQ * 4;
    float* mx2 = (float*)w;  w += (long)HEADS * SEQ * 4;
    float* rd2 = (float*)w;  w += (long)HEADS * SEQ * 4;
    uint32_t* mb = (uint32_t*)w; w += (long)HEADS * SEQ * 32 * 4; // 4MB
    float* S   = (float*)w;  w += (long)HEADS * SEQ * SEQ * 4;  // 134MB

    const float inv_sqrt_hd = 0.088388347648318447f; // 1/sqrt(128)

    dim3 gproj(DMODEL / 128, SEQ / 128, 1);
    // Q,K: fp32-precision split GEMM (mask decisions depend on them)
    gemm_f16<true, 1><<<gproj, 256, 0, stream>>>(hs, Wq, Qr, DMODEL, DMODEL, 0, 0, 0, 1.f);
    gemm_f16<true, 1><<<gproj, 256, 0, stream>>>(hs, Wk, Kr, DMODEL, DMODEL, 0, 0, 0, 1.f);
    // V: plain f16 MFMA
    gemm_f16<false, 1><<<gproj, 256, 0, stream>>>(hs, Wv, V, DMODEL, DMODEL, 0, 0, 0, 1.f);

    rope_kernel<<<(HEADS * SEQ * 64) / 256, 256, 0, stream>>>(Qr, Kr);

    // S = Q K^T / sqrt(hd), split precision, batched over heads
    dim3 gsc(SEQ / 128, SEQ / 128, HEADS);
    gemm_f16<true, 0><<<gsc, 256, 0, stream>>>(Qr, Kr, S, HD, SEQ,
        (long)SEQ * HD, (long)SEQ * HD, (long)SEQ * SEQ, inv_sqrt_hd);

    stats_kernel<<<HEADS * SEQ, 64, 0, stream>>>(S, mb, mx1, rd1, 1);
    scan_kernel<<<HEADS, 64, 0, stream>>>(S, mx1, rd1, mb);
    stats_kernel<<<HEADS * SEQ, 64, 0, stream>>>(S, mb, mx2, rd2, 2);
    pv_kernel<<<dim3(SEQ / 64, HEADS), 256, 0, stream>>>(S, V, mb, mx2, rd2, ctx);

    // out = ctx Wo^T
    gemm_f16<false, 0><<<gproj, 256, 0, stream>>>(ctx, Wo, out, DMODEL, DMODEL, 0, 0, 0, 1.f);
}